// Round 2
// baseline (37.610 us; speedup 1.0000x reference)
//
#include <hip/hip_runtime.h>

// B=128, x1/x2/x3 (B,2048,7,7) f32, W (14,2048), b (14,)
// softmax over singleton axis == 1.0 exactly  =>  h = 2*x1 + x2  (x3 unused!)
// feats[b,n] = mean_c(2*x1 + x2) ; logits = feats @ W^T + b
// Output layout: logits (128*14) then feats (128*2048), f32 flat.
//
// Fused design: one block = 16 consecutive rows (n values) of one batch b.
// Block computes 16 feats values, then its partial logits[b, 0..13]
// contribution via atomicAdd (128 adds per logits element total).
// init_logits seeds logits = bias (replays must not accumulate).

#define NROWS (128 * 2048)
#define FC_B 128
#define FC_N 2048
#define FC_J 14

__global__ __launch_bounds__(256) void init_logits(const float* __restrict__ bias,
                                                   float* __restrict__ logits) {
    for (int i = threadIdx.x; i < FC_B * FC_J; i += 256)
        logits[i] = bias[i % FC_J];
}

__global__ __launch_bounds__(256) void fused_kernel(const float* __restrict__ x1,
                                                    const float* __restrict__ x2,
                                                    const float* __restrict__ W,
                                                    float* __restrict__ feats,
                                                    float* __restrict__ logits) {
    const int tid = threadIdx.x;
    const int g = tid >> 4;      // row group within block (0..15)
    const int t = tid & 15;      // lane within row group
    const int r = blockIdx.x * 16 + g;

    const float* p1 = x1 + (size_t)r * 49;
    const float* p2 = x2 + (size_t)r * 49;

    // 49 = 16*3 + 1 : lanes cover [t, t+16, t+32], lane 0 adds element 48
    float a = p1[t] + p1[t + 16] + p1[t + 32];
    float c = p2[t] + p2[t + 16] + p2[t + 32];
    if (t == 0) { a += p1[48]; c += p2[48]; }
    float v = 2.0f * a + c;

    #pragma unroll
    for (int m = 8; m >= 1; m >>= 1)
        v += __shfl_xor(v, m, 16);

    __shared__ float sf[16];
    if (t == 0) {
        const float fv = v * (1.0f / 49.0f);
        feats[r] = fv;
        sf[g] = fv;
    }
    __syncthreads();

    // partial fc: this block owns n in [n0, n0+16) of batch b
    if (tid < FC_J) {
        const int b = blockIdx.x >> 7;            // 128 blocks per batch row
        const int n0 = (blockIdx.x & 127) << 4;
        const float* wrow = W + tid * FC_N + n0;  // W is (14, 2048) row-major
        float acc = 0.0f;
        #pragma unroll
        for (int k = 0; k < 16; ++k)
            acc += sf[k] * wrow[k];
        atomicAdd(&logits[b * FC_J + tid], acc);
    }
}

extern "C" void kernel_launch(void* const* d_in, const int* in_sizes, int n_in,
                              void* d_out, int out_size, void* d_ws, size_t ws_size,
                              hipStream_t stream) {
    const float* x1 = (const float*)d_in[0];
    const float* x2 = (const float*)d_in[1];
    // d_in[2] = x3 — provably unused (softmax over singleton axis == 1)
    const float* W = (const float*)d_in[3];
    const float* bias = (const float*)d_in[4];

    float* out = (float*)d_out;
    float* logits = out;                 // 128*14
    float* feats = out + FC_B * FC_J;    // 128*2048

    init_logits<<<1, 256, 0, stream>>>(bias, logits);
    fused_kernel<<<NROWS / 16, 256, 0, stream>>>(x1, x2, W, feats, logits);
}

// Round 3
// 26.102 us; speedup vs baseline: 1.4409x; 1.4409x over previous
//
#include <hip/hip_runtime.h>

// B=128, x1/x2/x3 (B,2048,7,7) f32, W (14,2048), b (14,)
// softmax over singleton axis == 1.0 exactly  =>  h = 2*x1 + x2  (x3 unused!)
// feats[b,n] = mean_c(2*x1 + x2) ; logits = feats @ W^T + b
// Output layout: logits (128*14) then feats (128*2048), f32 flat.
//
// Round-3 design: fused feats + fc-partials, NO atomics (round 2 showed
// 229k atomics onto 112 cache lines serialize to ~40us). Each 1024-thread
// block owns 64 consecutive rows of one batch b, writes 14 partial dot
// products to d_ws; a tiny gather kernel reduces 32 partials per logit.

#define NROWS (128 * 2048)
#define FC_B 128
#define FC_N 2048
#define FC_J 14
#define RPB 64                   // rows per block
#define NBLK (NROWS / RPB)       // 4096 blocks
#define BPB (FC_N / RPB)         // 32 blocks per batch row

__global__ __launch_bounds__(1024) void fused_kernel(const float* __restrict__ x1,
                                                     const float* __restrict__ x2,
                                                     const float* __restrict__ W,
                                                     float* __restrict__ feats,
                                                     float* __restrict__ part) {
    const int tid = threadIdx.x;
    const int g = tid >> 4;      // row group within block (0..63)
    const int t = tid & 15;      // lane within row group
    const int r = blockIdx.x * RPB + g;

    const float* p1 = x1 + (size_t)r * 49;
    const float* p2 = x2 + (size_t)r * 49;

    // 49 = 16*3 + 1 : lanes cover [t, t+16, t+32], lane 0 adds element 48.
    // Per wave, each load instruction pulls 4 fully-consumed 64B lines.
    float a = p1[t] + p1[t + 16] + p1[t + 32];
    float c = p2[t] + p2[t + 16] + p2[t + 32];
    if (t == 0) { a += p1[48]; c += p2[48]; }
    float v = 2.0f * a + c;

    #pragma unroll
    for (int m = 8; m >= 1; m >>= 1)
        v += __shfl_xor(v, m, 16);

    __shared__ float sf[RPB];
    if (t == 0) {
        const float fv = v * (1.0f / 49.0f);
        feats[r] = fv;
        sf[g] = fv;
    }
    __syncthreads();

    // fc partial: this block owns n in [n0, n0+64) of batch b. Non-atomic
    // private slot per block — gather kernel reduces.
    if (tid < FC_J) {
        const int n0 = (blockIdx.x & (BPB - 1)) * RPB;
        const float* wrow = W + tid * FC_N + n0;   // W is (14, 2048) row-major
        float acc = 0.0f;
        #pragma unroll
        for (int k = 0; k < RPB; ++k)
            acc += sf[k] * wrow[k];
        part[blockIdx.x * FC_J + tid] = acc;
    }
}

__global__ __launch_bounds__(256) void gather_kernel(const float* __restrict__ part,
                                                     const float* __restrict__ bias,
                                                     float* __restrict__ logits) {
    const int idx = blockIdx.x * 256 + threadIdx.x;
    if (idx >= FC_B * FC_J) return;
    const int b = idx / FC_J;
    const int j = idx % FC_J;
    float s = bias[j];
    #pragma unroll
    for (int i = 0; i < BPB; ++i)
        s += part[(size_t)(b * BPB + i) * FC_J + j];
    logits[idx] = s;
}

extern "C" void kernel_launch(void* const* d_in, const int* in_sizes, int n_in,
                              void* d_out, int out_size, void* d_ws, size_t ws_size,
                              hipStream_t stream) {
    const float* x1 = (const float*)d_in[0];
    const float* x2 = (const float*)d_in[1];
    // d_in[2] = x3 — provably unused (softmax over singleton axis == 1)
    const float* W = (const float*)d_in[3];
    const float* bias = (const float*)d_in[4];

    float* out = (float*)d_out;
    float* logits = out;                 // 128*14
    float* feats = out + FC_B * FC_J;    // 128*2048

    float* part = (float*)d_ws;          // NBLK*FC_J*4 = 229 KB scratch

    fused_kernel<<<NBLK, 1024, 0, stream>>>(x1, x2, W, feats, part);
    gather_kernel<<<(FC_B * FC_J + 255) / 256, 256, 0, stream>>>(part, bias, logits);
}

// Round 4
// 24.054 us; speedup vs baseline: 1.5636x; 1.0851x over previous
//
#include <hip/hip_runtime.h>

// B=128, x1/x2/x3 (B,2048,7,7) f32, W (14,2048), b (14,)
// softmax over singleton axis == 1.0 exactly  =>  h = 2*x1 + x2  (x3 unused!)
// feats[b,n] = mean_c(2*x1 + x2) ; logits = feats @ W^T + b
// Output layout: logits (128*14) then feats (128*2048), f32 flat.
//
// Round-4: single-pass residency. 2048 blocks x 256 thr = exactly 8 blocks/CU,
// all resident at once (no sequential block slots, no per-64-row barrier).
// Each block owns 128 consecutive rows of ONE batch. 16-lane butterfly leaves
// the row sum in ALL lanes, so lanes j<14 carry fc partials in registers
// across all 8 iterations; one LDS reduce + one partial write per block.
// Gather: 16 partials per logit (no atomics -- round 2 showed same-line
// atomics serialize at ~47cy/op).

#define NROWS (128 * 2048)
#define FC_B 128
#define FC_N 2048
#define FC_J 14
#define GROUPS 16                        // 16-lane row groups per block
#define ITERS 8
#define ROWS_PER_BLOCK (GROUPS * ITERS)  // 128
#define NBLK (NROWS / ROWS_PER_BLOCK)    // 2048
#define BLK_PER_B (FC_N / ROWS_PER_BLOCK) // 16 blocks per batch row

__global__ __launch_bounds__(256, 8) void fused_kernel(const float* __restrict__ x1,
                                                       const float* __restrict__ x2,
                                                       const float* __restrict__ W,
                                                       float* __restrict__ feats,
                                                       float* __restrict__ part) {
    const int tid = threadIdx.x;
    const int g = tid >> 4;      // group (0..15)
    const int t = tid & 15;      // lane within group
    const int rbase = blockIdx.x * ROWS_PER_BLOCK;

    const float* wrow = W + (t < FC_J ? t : 0) * FC_N;  // lane j's W row
    float accj = 0.0f;

    #pragma unroll
    for (int it = 0; it < ITERS; ++it) {
        const int r = rbase + it * GROUPS + g;
        const float* p1 = x1 + (size_t)r * 49;
        const float* p2 = x2 + (size_t)r * 49;

        // 49 = 16*3 + 1 : lanes cover [t, t+16, t+32], lane 0 adds elem 48
        float a = p1[t] + p1[t + 16] + p1[t + 32];
        float c = p2[t] + p2[t + 16] + p2[t + 32];
        if (t == 0) { a += p1[48]; c += p2[48]; }
        float v = 2.0f * a + c;

        // butterfly: ALL 16 lanes end with the group sum
        #pragma unroll
        for (int m = 8; m >= 1; m >>= 1)
            v += __shfl_xor(v, m, 16);

        const float fv = v * (1.0f / 49.0f);
        if (t == 0) feats[r] = fv;
        if (t < FC_J) accj += fv * wrow[r & (FC_N - 1)];  // W is L2-resident
    }

    __shared__ float sp[GROUPS][FC_J];
    if (t < FC_J) sp[g][t] = accj;
    __syncthreads();

    if (tid < FC_J) {
        float s = 0.0f;
        #pragma unroll
        for (int k = 0; k < GROUPS; ++k) s += sp[k][tid];
        part[blockIdx.x * FC_J + tid] = s;
    }
}

__global__ __launch_bounds__(256) void gather_kernel(const float* __restrict__ part,
                                                     const float* __restrict__ bias,
                                                     float* __restrict__ logits) {
    const int idx = blockIdx.x * 256 + threadIdx.x;
    if (idx >= FC_B * FC_J) return;
    const int b = idx / FC_J;
    const int j = idx % FC_J;
    float s = bias[j];
    #pragma unroll
    for (int i = 0; i < BLK_PER_B; ++i)
        s += part[(size_t)(b * BLK_PER_B + i) * FC_J + j];
    logits[idx] = s;
}

extern "C" void kernel_launch(void* const* d_in, const int* in_sizes, int n_in,
                              void* d_out, int out_size, void* d_ws, size_t ws_size,
                              hipStream_t stream) {
    const float* x1 = (const float*)d_in[0];
    const float* x2 = (const float*)d_in[1];
    // d_in[2] = x3 — provably unused (softmax over singleton axis == 1)
    const float* W = (const float*)d_in[3];
    const float* bias = (const float*)d_in[4];

    float* out = (float*)d_out;
    float* logits = out;                 // 128*14
    float* feats = out + FC_B * FC_J;    // 128*2048

    float* part = (float*)d_ws;          // NBLK*FC_J*4 = 114 KB scratch

    fused_kernel<<<NBLK, 256, 0, stream>>>(x1, x2, W, feats, part);
    gather_kernel<<<(FC_B * FC_J + 255) / 256, 256, 0, stream>>>(part, bias, logits);
}

// Round 5
// 23.857 us; speedup vs baseline: 1.5765x; 1.0082x over previous
//
#include <hip/hip_runtime.h>

// B=128, x1/x2/x3 (B,2048,7,7) f32, W (14,2048), b (14,)
// softmax over singleton axis == 1.0 exactly  =>  h = 2*x1 + x2  (x3 unused!)
// feats[b,n] = mean_c(2*x1 + x2) ; logits = feats @ W^T + b
// Output layout: logits (128*14) then feats (128*2048), f32 flat.
//
// Round-5: round 4 was load-ISSUE-bound (scalar 4B loads, 196B row stride =>
// every 64B segment straddles lines; 38us at 1.4TB/s, VALU 6%). Fix:
// decouple load from row structure. 64-row tile = 3136 floats = 784 aligned
// float4 per array. Phase 1: coalesced float4 stream, combine 2*x1+x2,
// park in LDS. Phase 2: 4 thr/row sum 12 strided LDS elems + tail, shuffle
// reduce. Phase 3: fc partials (no atomics -- round 2: same-line atomics
// serialize ~47cy/op).

#define NROWS (128 * 2048)
#define FC_B 128
#define FC_N 2048
#define FC_J 14
#define RPB 64                          // rows per block
#define TILE_F (RPB * 49)               // 3136 floats
#define TILE_V (TILE_F / 4)             // 784 float4
#define NBLK (NROWS / RPB)              // 4096
#define BPB (FC_N / RPB)                // 32 blocks per batch row

__global__ __launch_bounds__(256) void fused_kernel(const float* __restrict__ x1,
                                                    const float* __restrict__ x2,
                                                    const float* __restrict__ W,
                                                    float* __restrict__ feats,
                                                    float* __restrict__ part) {
    const int tid = threadIdx.x;
    __shared__ float sm[TILE_F];
    __shared__ float sf[RPB];

    // ---- Phase 1: coalesced float4 stream -> LDS (combined 2*x1+x2) ----
    const float4* q1 = (const float4*)x1 + (size_t)blockIdx.x * TILE_V;
    const float4* q2 = (const float4*)x2 + (size_t)blockIdx.x * TILE_V;
    float4* smv = (float4*)sm;

    #pragma unroll
    for (int k = 0; k < 3; ++k) {            // 3*256 = 768
        const int i = k * 256 + tid;
        const float4 a = q1[i];
        const float4 c = q2[i];
        float4 v;
        v.x = 2.0f * a.x + c.x;
        v.y = 2.0f * a.y + c.y;
        v.z = 2.0f * a.z + c.z;
        v.w = 2.0f * a.w + c.w;
        smv[i] = v;
    }
    if (tid < TILE_V - 768) {                // tail: 16 float4
        const int i = 768 + tid;
        const float4 a = q1[i];
        const float4 c = q2[i];
        float4 v;
        v.x = 2.0f * a.x + c.x;
        v.y = 2.0f * a.y + c.y;
        v.z = 2.0f * a.z + c.z;
        v.w = 2.0f * a.w + c.w;
        smv[i] = v;
    }
    __syncthreads();

    // ---- Phase 2: row sums. 4 threads per row, stride-4 over 48 + tail ----
    const int row = tid >> 2;                // 0..63
    const int t = tid & 3;
    const float* rp = sm + row * 49;
    float v = 0.0f;
    #pragma unroll
    for (int k = 0; k < 12; ++k)
        v += rp[t + 4 * k];
    if (t == 0) v += rp[48];

    v += __shfl_xor(v, 1, 4);
    v += __shfl_xor(v, 2, 4);

    if (t == 0) {
        const float fv = v * (1.0f / 49.0f);
        feats[(size_t)blockIdx.x * RPB + row] = fv;
        sf[row] = fv;
    }
    __syncthreads();

    // ---- Phase 3: fc partials (this block owns n in [n0, n0+64) of batch b)
    if (tid < FC_J) {
        const int n0 = (blockIdx.x & (BPB - 1)) * RPB;
        const float* wrow = W + tid * FC_N + n0;   // L2-resident (112 KB)
        float acc = 0.0f;
        #pragma unroll
        for (int k = 0; k < RPB; ++k)
            acc += sf[k] * wrow[k];
        part[(size_t)blockIdx.x * FC_J + tid] = acc;
    }
}

__global__ __launch_bounds__(256) void gather_kernel(const float* __restrict__ part,
                                                     const float* __restrict__ bias,
                                                     float* __restrict__ logits) {
    const int idx = blockIdx.x * 256 + threadIdx.x;
    if (idx >= FC_B * FC_J) return;
    const int b = idx / FC_J;
    const int j = idx % FC_J;
    float s = bias[j];
    #pragma unroll
    for (int i = 0; i < BPB; ++i)
        s += part[(size_t)(b * BPB + i) * FC_J + j];
    logits[idx] = s;
}

extern "C" void kernel_launch(void* const* d_in, const int* in_sizes, int n_in,
                              void* d_out, int out_size, void* d_ws, size_t ws_size,
                              hipStream_t stream) {
    const float* x1 = (const float*)d_in[0];
    const float* x2 = (const float*)d_in[1];
    // d_in[2] = x3 — provably unused (softmax over singleton axis == 1)
    const float* W = (const float*)d_in[3];
    const float* bias = (const float*)d_in[4];

    float* out = (float*)d_out;
    float* logits = out;                 // 128*14
    float* feats = out + FC_B * FC_J;    // 128*2048

    float* part = (float*)d_ws;          // NBLK*FC_J*4 = 229 KB scratch

    fused_kernel<<<NBLK, 256, 0, stream>>>(x1, x2, W, feats, part);
    gather_kernel<<<(FC_B * FC_J + 255) / 256, 256, 0, stream>>>(part, bias, logits);
}